// Round 12
// baseline (268.264 us; speedup 1.0000x reference)
//
#include <hip/hip_runtime.h>
#include <stdint.h>

#define NPTS 8192
#define NPAIR 4096
#define NB 4
#define KNN 16
#define RQ 4          // queries (rows) per wave
#define CAP 512       // per-query u16 survivor buffer
#define TRIG 256      // tighten when cnt >= TRIG (checked every 2 pair-steps: +256 max -> <= 512)
#define NSLOT 8       // CAP / 64

typedef unsigned long long u64;
typedef unsigned int u32;
typedef unsigned short u16;

__device__ __forceinline__ u32 f2ord(float f) {
    u32 b = __float_as_uint(f);
    return (b & 0x80000000u) ? ~b : (b | 0x80000000u);
}
__device__ __forceinline__ float ord2f(u32 u) {
    u32 b = (u & 0x80000000u) ? (u & 0x7fffffffu) : ~u;
    return __uint_as_float(b);
}
__device__ __forceinline__ u64 shflx64(u64 v, int m) {
    u32 lo = (u32)v, hi = (u32)(v >> 32);
    lo = __shfl_xor(lo, m, 64);
    hi = __shfl_xor(hi, m, 64);
    return ((u64)hi << 32) | lo;
}

// Pair-packed SoA: pos8[(b*NPAIR+m)*2+0] = {x0,x1,y0,y1}, +1 = {z0,z1,sq0,sq1}.
// sq via mul-add chain (np.sum(p*p)): ((x*x + y*y) + z*z), all _rn.
__global__ __launch_bounds__(256) void pack_kernel(const float* __restrict__ pos,
                                                   float4* __restrict__ pos8) {
    int t = blockIdx.x * 256 + threadIdx.x;   // 0..16383
    int b = t >> 12;
    int m = t & (NPAIR - 1);
    const float* p = pos + (size_t)b * 3 * NPTS;
    float2 x = *(const float2*)&p[2 * m];
    float2 y = *(const float2*)&p[NPTS + 2 * m];
    float2 z = *(const float2*)&p[2 * NPTS + 2 * m];
    float s0 = __fadd_rn(__fadd_rn(__fmul_rn(x.x, x.x), __fmul_rn(y.x, y.x)), __fmul_rn(z.x, z.x));
    float s1 = __fadd_rn(__fadd_rn(__fmul_rn(x.y, x.y), __fmul_rn(y.y, y.y)), __fmul_rn(z.y, z.y));
    pos8[2 * t]     = make_float4(x.x, x.y, y.x, y.y);
    pos8[2 * t + 1] = make_float4(z.x, z.y, s0, s1);
}

// reference-exact distance for candidate pair (a,c) against query r
#define DIST(r, a, c, d0, d1)                                                           \
    { float dot0 = __fmaf_rn(qz[r], (c).x, __fmaf_rn(qy[r], (a).z, __fmul_rn(qx[r], (a).x))); \
      float dot1 = __fmaf_rn(qz[r], (c).y, __fmaf_rn(qy[r], (a).w, __fmul_rn(qx[r], (a).y))); \
      d0 = __fsub_rn(__fadd_rn(qw[r], (c).z), __fmul_rn(2.0f, dot0));                   \
      d1 = __fsub_rn(__fadd_rn(qw[r], (c).w), __fmul_rn(2.0f, dot1)); }

// recompute d2 for stored candidate index
#define RECOMP(r, idx, d2out)                                                           \
    { int _m = (int)(idx) >> 1, _h = (int)(idx) & 1;                                    \
      float4 _a = P8[2 * _m], _c = P8[2 * _m + 1];                                      \
      float _px = _h ? _a.y : _a.x, _py = _h ? _a.w : _a.z;                             \
      float _pz = _h ? _c.y : _c.x, _pw = _h ? _c.w : _c.z;                             \
      float _dot = __fmaf_rn(qz[r], _pz, __fmaf_rn(qy[r], _py, __fmul_rn(qx[r], _px))); \
      d2out = __fsub_rn(__fadd_rn(qw[r], _pw), __fmul_rn(2.0f, _dot)); }

// One wave serves RQ=4 consecutive query rows: every candidate pair loaded once
// feeds 8 query-candidate distances (L2 traffic /4). Survivors (d2 < T[r]) go
// to per-query u16 index buffers via ballot-append; d2 is recomputed (exact
// same arithmetic) whenever needed. Threshold tightening: T' = d2 of the
// 16th-smallest per-lane-min (cross-lane bitonic sort of 64 mins). Exactness:
// >=16 buffer entries have key <= T'-key; all buffered entries have smaller
// indices than any future candidate, so ties lose -> pruning d2 >= T' exact.
__global__ __launch_bounds__(256) void knn_kernel(const float4* __restrict__ pos8,
                                                  float* __restrict__ out) {
    __shared__ u16 buf[4][RQ][CAP];
    const int lane = threadIdx.x & 63;
    const int wv = threadIdx.x >> 6;
    const int rowbase = blockIdx.x * 16 + wv * RQ;   // 16 rows per block
    const int b = rowbase >> 13;
    const int ib = rowbase & (NPTS - 1);
    const float4* __restrict__ P8 = pos8 + (size_t)b * NPAIR * 2;
    const u64 below = (1ull << lane) - 1ull;

    // query registers (wave-uniform values)
    float qx[RQ], qy[RQ], qz[RQ], qw[RQ];
#pragma unroll
    for (int r = 0; r < RQ; ++r) {
        int iq = ib + r, m = iq >> 1, h = iq & 1;
        float4 a = P8[2 * m], c = P8[2 * m + 1];
        qx[r] = h ? a.y : a.x;
        qy[r] = h ? a.w : a.z;
        qz[r] = h ? c.y : c.x;
        qw[r] = h ? c.w : c.z;
    }

    float T[RQ];
    int cnt[RQ];

    // 16th-smallest of the 64 per-lane values (u32), via bitonic sort + bcast
    auto rank16 = [&](u32 v) -> u32 {
#pragma unroll
        for (int k = 2; k <= 64; k <<= 1)
#pragma unroll
            for (int j = k >> 1; j >= 1; j >>= 1) {
                u32 o = __shfl_xor(v, j, 64);
                bool up = ((lane & k) == 0) == ((lane & j) == 0);
                v = (up ? (v < o) : (v > o)) ? v : o;
            }
        return (u32)__shfl((int)v, 15, 64);
    };

    // tighten query r: recompute ords, T' = 16th lane-min, compact to <= T'.
    // Fallback (adversarial): exact 16-round extract-min on u64 keys.
    auto tighten = [&](int r) {
        u32 ordv[NSLOT], idxv[NSLOT];
        u32 mn = 0xFFFFFFFFu;
#pragma unroll
        for (int t = 0; t < NSLOT; ++t) {
            int bi = t * 64 + lane;
            bool val = bi < cnt[r];
            u32 idx = val ? (u32)buf[wv][r][bi] : 0u;
            float d2;
            RECOMP(r, idx, d2);
            u32 o = val ? f2ord(d2) : 0xFFFFFFFFu;
            ordv[t] = o; idxv[t] = idx;
            mn = o < mn ? o : mn;
        }
        u32 hi = rank16(mn);
        int rc = 0;
#pragma unroll
        for (int t = 0; t < NSLOT; ++t) rc += (int)__popcll(__ballot(ordv[t] <= hi));
        if (rc <= TRIG) {
            int nc = 0;
#pragma unroll
            for (int t = 0; t < NSLOT; ++t) {
                bool keep = ordv[t] <= hi;
                u64 bal = __ballot(keep);
                if (keep) buf[wv][r][nc + (int)__popcll(bal & below)] = (u16)idxv[t];
                nc += (int)__popcll(bal);
            }
            cnt[r] = nc;
            T[r] = ord2f(hi);
        } else {
            u64 s8[NSLOT];
#pragma unroll
            for (int t = 0; t < NSLOT; ++t) s8[t] = ((u64)ordv[t] << 13) | idxv[t];
            u64 mm = 0;
#pragma unroll 1
            for (int rr = 0; rr < KNN; ++rr) {
                u64 lm = s8[0];
#pragma unroll
                for (int t = 1; t < NSLOT; ++t) lm = s8[t] < lm ? s8[t] : lm;
                mm = lm;
#pragma unroll
                for (int s = 1; s < 64; s <<= 1) { u64 o = shflx64(mm, s); mm = o < mm ? o : mm; }
#pragma unroll
                for (int t = 0; t < NSLOT; ++t) s8[t] = (s8[t] == mm) ? ~0ULL : s8[t];
                if (lane == 0) buf[wv][r][rr] = (u16)(mm & (u64)(NPTS - 1));
            }
            cnt[r] = KNN;
            T[r] = ord2f((u32)(mm >> 13));
        }
    };

    // ---- bootstrap: candidates 0..511 (pairs 0..255) in registers ----
    {
        float d2v[RQ][8];
#pragma unroll
        for (int s = 0; s < 4; ++s) {
            int m = s * 64 + lane;
            float4 a = P8[2 * m], c = P8[2 * m + 1];
#pragma unroll
            for (int r = 0; r < RQ; ++r) DIST(r, a, c, d2v[r][2 * s], d2v[r][2 * s + 1]);
        }
#pragma unroll
        for (int r = 0; r < RQ; ++r) {
            u32 mn = 0xFFFFFFFFu;
#pragma unroll
            for (int t = 0; t < 8; ++t) { u32 o = f2ord(d2v[r][t]); mn = o < mn ? o : mn; }
            u32 hi = rank16(mn);
            int nc = 0;
#pragma unroll
            for (int t = 0; t < 8; ++t) {
                bool keep = f2ord(d2v[r][t]) <= hi;
                u64 bal = __ballot(keep);
                if (keep)
                    buf[wv][r][nc + (int)__popcll(bal & below)] =
                        (u16)(2 * ((t >> 1) * 64 + lane) + (t & 1));
                nc += (int)__popcll(bal);
            }
            cnt[r] = nc;
            T[r] = ord2f(hi);
        }
    }

    // ---- steady scan: pair-steps 4..63, filter + ballot-append ----
#pragma unroll 1
    for (int g = 4; g < 64; g += 2) {
#pragma unroll
        for (int r = 0; r < RQ; ++r)
            if (cnt[r] >= TRIG) tighten(r);   // wave-uniform branch
        int m0 = g * 64 + lane, m1 = (g + 1) * 64 + lane;
        float4 a0 = P8[2 * m0], c0 = P8[2 * m0 + 1];
        float4 a1 = P8[2 * m1], c1 = P8[2 * m1 + 1];
#pragma unroll
        for (int r = 0; r < RQ; ++r) {
            float d0, d1, d2_, d3;
            DIST(r, a0, c0, d0, d1);
            DIST(r, a1, c1, d2_, d3);
            bool p0 = d0 < T[r], p1 = d1 < T[r], p2 = d2_ < T[r], p3 = d3 < T[r];
            u64 b0 = __ballot(p0), b1 = __ballot(p1);
            u64 b2 = __ballot(p2), b3 = __ballot(p3);
            if (b0 | b1 | b2 | b3) {
                int base = cnt[r];
                int c0n = (int)__popcll(b0), c1n = (int)__popcll(b1), c2n = (int)__popcll(b2);
                if (p0) buf[wv][r][base + (int)__popcll(b0 & below)] = (u16)(2 * m0);
                if (p1) buf[wv][r][base + c0n + (int)__popcll(b1 & below)] = (u16)(2 * m0 + 1);
                if (p2) buf[wv][r][base + c0n + c1n + (int)__popcll(b2 & below)] = (u16)(2 * m1);
                if (p3) buf[wv][r][base + c0n + c1n + c2n + (int)__popcll(b3 & below)] = (u16)(2 * m1 + 1);
                cnt[r] = base + c0n + c1n + c2n + (int)__popcll(b3);
            }
        }
    }

    // ---- final per query: compact if large, then bitonic sort-64 on keys ----
#pragma unroll
    for (int r = 0; r < RQ; ++r) {
        if (cnt[r] > 64) tighten(r);          // typical: compacts to ~16-30
        u64 myk;
        if (cnt[r] <= 64) {
            bool val = lane < cnt[r];
            u32 idx = val ? (u32)buf[wv][r][lane] : 0u;
            float d2;
            RECOMP(r, idx, d2);
            u64 v = val ? (((u64)f2ord(d2) << 13) | idx) : ~0ULL;
#pragma unroll
            for (int k = 2; k <= 64; k <<= 1)
#pragma unroll
                for (int j = k >> 1; j >= 1; j >>= 1) {
                    u64 o = shflx64(v, j);
                    bool up = ((lane & k) == 0) == ((lane & j) == 0);
                    v = (up ? (v < o) : (v > o)) ? v : o;
                }
            myk = v;   // lane holds rank = lane
        } else {
            // adversarial path: exact extract-min tournament over <= 512 keys
            u64 s8[NSLOT];
#pragma unroll
            for (int t = 0; t < NSLOT; ++t) {
                int bi = t * 64 + lane;
                bool val = bi < cnt[r];
                u32 idx = val ? (u32)buf[wv][r][bi] : 0u;
                float d2;
                RECOMP(r, idx, d2);
                s8[t] = val ? (((u64)f2ord(d2) << 13) | idx) : ~0ULL;
            }
            myk = ~0ULL;
#pragma unroll 1
            for (int rr = 0; rr < KNN; ++rr) {
                u64 lm = s8[0];
#pragma unroll
                for (int t = 1; t < NSLOT; ++t) lm = s8[t] < lm ? s8[t] : lm;
                u64 mm = lm;
#pragma unroll
                for (int s = 1; s < 64; s <<= 1) { u64 o = shflx64(mm, s); mm = o < mm ? o : mm; }
#pragma unroll
                for (int t = 0; t < NSLOT; ++t) s8[t] = (s8[t] == mm) ? ~0ULL : s8[t];
                if (lane == rr) myk = mm;
            }
        }
        if (lane < KNN) {
            int iq = ib + r;
            size_t o1 = (size_t)(b * KNN + lane) * NPTS + iq;
            out[o1] = (float)(u32)(myk & (u64)(NPTS - 1));
            out[(size_t)NB * KNN * NPTS + o1] = ord2f((u32)(myk >> 13));
        }
    }
}

extern "C" void kernel_launch(void* const* d_in, const int* in_sizes, int n_in,
                              void* d_out, int out_size, void* d_ws, size_t ws_size,
                              hipStream_t stream) {
    const float* pos = (const float*)d_in[0];
    float* out = (float*)d_out;
    float4* pos8 = (float4*)d_ws;   // 4*4096*2*16 B = 512 KB scratch

    pack_kernel<<<dim3(NB * NPAIR / 256), dim3(256), 0, stream>>>(pos, pos8);
    knn_kernel<<<dim3(NB * NPTS / 16), dim3(256), 0, stream>>>(pos8, out);
}

// Round 13
// 239.217 us; speedup vs baseline: 1.1214x; 1.1214x over previous
//
#include <hip/hip_runtime.h>
#include <stdint.h>

#define NPTS 8192
#define NPAIR 4096
#define NB 4
#define KNN 16
#define RQ 2          // queries (rows) per wave; one point-pair load = both queries
#define CAP 512       // per-query u16 survivor buffer
#define TRIG 384      // tighten when cnt >= TRIG (checked every pair-step, max +128 -> <= 512)
#define NSLOT 8       // CAP / 64

typedef unsigned long long u64;
typedef unsigned int u32;
typedef unsigned short u16;

__device__ __forceinline__ u32 f2ord(float f) {
    u32 b = __float_as_uint(f);
    return (b & 0x80000000u) ? ~b : (b | 0x80000000u);
}
__device__ __forceinline__ float ord2f(u32 u) {
    u32 b = (u & 0x80000000u) ? (u & 0x7fffffffu) : ~u;
    return __uint_as_float(b);
}
__device__ __forceinline__ u64 shflx64(u64 v, int m) {
    u32 lo = (u32)v, hi = (u32)(v >> 32);
    lo = __shfl_xor(lo, m, 64);
    hi = __shfl_xor(hi, m, 64);
    return ((u64)hi << 32) | lo;
}

// Pair-packed SoA: pos8[(b*NPAIR+m)*2+0] = {x0,x1,y0,y1}, +1 = {z0,z1,sq0,sq1}.
// sq via mul-add chain (np.sum(p*p)): ((x*x + y*y) + z*z), all _rn.
__global__ __launch_bounds__(256) void pack_kernel(const float* __restrict__ pos,
                                                   float4* __restrict__ pos8) {
    int t = blockIdx.x * 256 + threadIdx.x;   // 0..16383
    int b = t >> 12;
    int m = t & (NPAIR - 1);
    const float* p = pos + (size_t)b * 3 * NPTS;
    float2 x = *(const float2*)&p[2 * m];
    float2 y = *(const float2*)&p[NPTS + 2 * m];
    float2 z = *(const float2*)&p[2 * NPTS + 2 * m];
    float s0 = __fadd_rn(__fadd_rn(__fmul_rn(x.x, x.x), __fmul_rn(y.x, y.x)), __fmul_rn(z.x, z.x));
    float s1 = __fadd_rn(__fadd_rn(__fmul_rn(x.y, x.y), __fmul_rn(y.y, y.y)), __fmul_rn(z.y, z.y));
    pos8[2 * t]     = make_float4(x.x, x.y, y.x, y.y);
    pos8[2 * t + 1] = make_float4(z.x, z.y, s0, s1);
}

// reference-exact distance for candidate pair (a,c) against query r
#define DIST(r, a, c, d0, d1)                                                           \
    { float dot0 = __fmaf_rn(qz[r], (c).x, __fmaf_rn(qy[r], (a).z, __fmul_rn(qx[r], (a).x))); \
      float dot1 = __fmaf_rn(qz[r], (c).y, __fmaf_rn(qy[r], (a).w, __fmul_rn(qx[r], (a).y))); \
      d0 = __fsub_rn(__fadd_rn(qw[r], (c).z), __fmul_rn(2.0f, dot0));                   \
      d1 = __fsub_rn(__fadd_rn(qw[r], (c).w), __fmul_rn(2.0f, dot1)); }

// recompute d2 for stored candidate index (bit-identical ops)
#define RECOMP(r, idx, d2out)                                                           \
    { int _m = (int)(idx) >> 1, _h = (int)(idx) & 1;                                    \
      float4 _a = P8[2 * _m], _c = P8[2 * _m + 1];                                      \
      float _px = _h ? _a.y : _a.x, _py = _h ? _a.w : _a.z;                             \
      float _pz = _h ? _c.y : _c.x, _pw = _h ? _c.w : _c.z;                             \
      float _dot = __fmaf_rn(qz[r], _pz, __fmaf_rn(qy[r], _py, __fmul_rn(qx[r], _px))); \
      d2out = __fsub_rn(__fadd_rn(qw[r], _pw), __fmul_rn(2.0f, _dot)); }

// One wave serves RQ=2 consecutive rows (one point-pair = both queries).
// Filter-and-defer with u16 index buffers; d2 recomputed when needed.
// Exactness: after every tighten, >=16 buffer entries have key <= T-key; all
// buffered entries precede future candidates in index, so ties lose ->
// pruning d2 >= T exact; discarded entries (d2 > T') have >=16 smaller keys.
__global__ __launch_bounds__(256) void knn_kernel(const float4* __restrict__ pos8,
                                                  float* __restrict__ out) {
    __shared__ u16 buf[4][RQ][CAP];
    const int lane = threadIdx.x & 63;
    const int wv = threadIdx.x >> 6;
    const int rowbase = blockIdx.x * 8 + wv * RQ;   // 8 rows per block (even)
    const int b = rowbase >> 13;
    const int ib = rowbase & (NPTS - 1);
    const float4* __restrict__ P8 = pos8 + (size_t)b * NPAIR * 2;
    const u64 below = (1ull << lane) - 1ull;

    // query registers: both rows come from one pair (ib even)
    float qx[RQ], qy[RQ], qz[RQ], qw[RQ];
    {
        int m = ib >> 1;
        float4 a = P8[2 * m], c = P8[2 * m + 1];
        qx[0] = a.x; qy[0] = a.z; qz[0] = c.x; qw[0] = c.z;
        qx[1] = a.y; qy[1] = a.w; qz[1] = c.y; qw[1] = c.w;
    }

    float T[RQ];
    int cnt[RQ];

    // 16th-smallest of the 64 per-lane values (u32), via bitonic sort + bcast
    auto rank16 = [&](u32 v) -> u32 {
#pragma unroll
        for (int k = 2; k <= 64; k <<= 1)
#pragma unroll
            for (int j = k >> 1; j >= 1; j >>= 1) {
                u32 o = __shfl_xor(v, j, 64);
                bool up = ((lane & k) == 0) == ((lane & j) == 0);
                v = (up ? (v < o) : (v > o)) ? v : o;
            }
        return (u32)__shfl((int)v, 15, 64);
    };

    // tighten query r: T' = 16th-smallest per-lane-min, compact to <= T'.
    // Fallback (adversarial): exact 16-round extract-min -> winners in buf.
    auto tighten = [&](int r) {
        u32 ordv[NSLOT], idxv[NSLOT];
        u32 mn = 0xFFFFFFFFu;
#pragma unroll
        for (int t = 0; t < NSLOT; ++t) {
            int bi = t * 64 + lane;
            bool val = bi < cnt[r];
            u32 idx = val ? (u32)buf[wv][r][bi] : 0u;
            float d2;
            RECOMP(r, idx, d2);
            u32 o = val ? f2ord(d2) : 0xFFFFFFFFu;
            ordv[t] = o; idxv[t] = idx;
            mn = o < mn ? o : mn;
        }
        u32 hi = rank16(mn);
        int rc = 0;
#pragma unroll
        for (int t = 0; t < NSLOT; ++t) rc += (int)__popcll(__ballot(ordv[t] <= hi));
        if (rc <= 256) {
            int nc = 0;
#pragma unroll
            for (int t = 0; t < NSLOT; ++t) {
                bool keep = ordv[t] <= hi;
                u64 bal = __ballot(keep);
                if (keep) buf[wv][r][nc + (int)__popcll(bal & below)] = (u16)idxv[t];
                nc += (int)__popcll(bal);
            }
            cnt[r] = nc;
            T[r] = ord2f(hi);
        } else {
            u64 s8[NSLOT];
#pragma unroll
            for (int t = 0; t < NSLOT; ++t) s8[t] = ((u64)ordv[t] << 13) | idxv[t];
            u64 mm = 0;
#pragma unroll 1
            for (int rr = 0; rr < KNN; ++rr) {
                u64 lm = s8[0];
#pragma unroll
                for (int t = 1; t < NSLOT; ++t) lm = s8[t] < lm ? s8[t] : lm;
                mm = lm;
#pragma unroll
                for (int s = 1; s < 64; s <<= 1) { u64 o = shflx64(mm, s); mm = o < mm ? o : mm; }
#pragma unroll
                for (int t = 0; t < NSLOT; ++t) s8[t] = (s8[t] == mm) ? ~0ULL : s8[t];
                if (lane == 0) buf[wv][r][rr] = (u16)(mm & (u64)(NPTS - 1));
            }
            cnt[r] = KNN;
            T[r] = ord2f((u32)(mm >> 13));
        }
    };

    // ---- bootstrap: candidates 0..511 (pairs 0..255) in registers ----
    {
        float d2v[RQ][8];
#pragma unroll
        for (int s = 0; s < 4; ++s) {
            int m = s * 64 + lane;
            float4 a = P8[2 * m], c = P8[2 * m + 1];
#pragma unroll
            for (int r = 0; r < RQ; ++r) DIST(r, a, c, d2v[r][2 * s], d2v[r][2 * s + 1]);
        }
#pragma unroll
        for (int r = 0; r < RQ; ++r) {
            u32 mn = 0xFFFFFFFFu;
#pragma unroll
            for (int t = 0; t < 8; ++t) { u32 o = f2ord(d2v[r][t]); mn = o < mn ? o : mn; }
            u32 hi = rank16(mn);
            int nc = 0;
#pragma unroll
            for (int t = 0; t < 8; ++t) {
                bool keep = f2ord(d2v[r][t]) <= hi;
                u64 bal = __ballot(keep);
                if (keep)
                    buf[wv][r][nc + (int)__popcll(bal & below)] =
                        (u16)(2 * ((t >> 1) * 64 + lane) + (t & 1));
                nc += (int)__popcll(bal);
            }
            cnt[r] = nc;
            T[r] = ord2f(hi);
        }
    }

    // ---- steady scan: pair-steps 4..63 (one pair load feeds both queries) ----
#pragma unroll 1
    for (int g = 4; g < 64; ++g) {
        int m = g * 64 + lane;
        float4 a = P8[2 * m], c = P8[2 * m + 1];
#pragma unroll
        for (int r = 0; r < RQ; ++r) {
            float d0, d1;
            DIST(r, a, c, d0, d1);
            bool p0 = d0 < T[r], p1 = d1 < T[r];
            u64 b0 = __ballot(p0), b1 = __ballot(p1);
            if (b0 | b1) {
                int base = cnt[r];
                int c0n = (int)__popcll(b0);
                if (p0) buf[wv][r][base + (int)__popcll(b0 & below)] = (u16)(2 * m);
                if (p1) buf[wv][r][base + c0n + (int)__popcll(b1 & below)] = (u16)(2 * m + 1);
                cnt[r] = base + c0n + (int)__popcll(b1);
                if (cnt[r] >= TRIG) tighten(r);   // max +128/step keeps <= CAP
            }
        }
    }

    // ---- final per query: compact if large, then bitonic sort-64 on keys ----
#pragma unroll
    for (int r = 0; r < RQ; ++r) {
        if (cnt[r] > 64) tighten(r);          // typical result: ~16-30 entries
        u64 myk = ~0ULL;
        if (cnt[r] <= 64) {
            bool val = lane < cnt[r];
            u32 idx = val ? (u32)buf[wv][r][lane] : 0u;
            float d2;
            RECOMP(r, idx, d2);
            u64 v = val ? (((u64)f2ord(d2) << 13) | idx) : ~0ULL;
#pragma unroll
            for (int k = 2; k <= 64; k <<= 1)
#pragma unroll
                for (int j = k >> 1; j >= 1; j >>= 1) {
                    u64 o = shflx64(v, j);
                    bool up = ((lane & k) == 0) == ((lane & j) == 0);
                    v = (up ? (v < o) : (v > o)) ? v : o;
                }
            myk = v;   // lane holds rank = lane
        } else {
            // adversarial path: exact extract-min tournament over <= 256 keys
            u64 s8[NSLOT];
#pragma unroll
            for (int t = 0; t < NSLOT; ++t) {
                int bi = t * 64 + lane;
                bool val = bi < cnt[r];
                u32 idx = val ? (u32)buf[wv][r][bi] : 0u;
                float d2;
                RECOMP(r, idx, d2);
                s8[t] = val ? (((u64)f2ord(d2) << 13) | idx) : ~0ULL;
            }
#pragma unroll 1
            for (int rr = 0; rr < KNN; ++rr) {
                u64 lm = s8[0];
#pragma unroll
                for (int t = 1; t < NSLOT; ++t) lm = s8[t] < lm ? s8[t] : lm;
                u64 mm = lm;
#pragma unroll
                for (int s = 1; s < 64; s <<= 1) { u64 o = shflx64(mm, s); mm = o < mm ? o : mm; }
#pragma unroll
                for (int t = 0; t < NSLOT; ++t) s8[t] = (s8[t] == mm) ? ~0ULL : s8[t];
                if (lane == rr) myk = mm;
            }
        }
        if (lane < KNN) {
            int iq = ib + r;
            size_t o1 = (size_t)(b * KNN + lane) * NPTS + iq;
            out[o1] = (float)(u32)(myk & (u64)(NPTS - 1));
            out[(size_t)NB * KNN * NPTS + o1] = ord2f((u32)(myk >> 13));
        }
    }
}

extern "C" void kernel_launch(void* const* d_in, const int* in_sizes, int n_in,
                              void* d_out, int out_size, void* d_ws, size_t ws_size,
                              hipStream_t stream) {
    const float* pos = (const float*)d_in[0];
    float* out = (float*)d_out;
    float4* pos8 = (float4*)d_ws;   // 4*4096*2*16 B = 512 KB scratch

    pack_kernel<<<dim3(NB * NPAIR / 256), dim3(256), 0, stream>>>(pos, pos8);
    knn_kernel<<<dim3(NB * NPTS / 8), dim3(256), 0, stream>>>(pos8, out);
}